// Round 5
// baseline (598.666 us; speedup 1.0000x reference)
//
#include <hip/hip_runtime.h>

// ---------------------------------------------------------------------------
// ScaledDotProductAttention: B=8, Sq=Sk=2048, D=E=1024, f32 in/out.
// Round 7: split-softmax fusion. QK kernel stores tile-max-relative logits in
// bf16 (Pb slot) + per-(row,tile) (max, sumexp) stats; sm_finalize combines
// stats, writes f32 weights + normalized bf16 Pb in place. Eliminates the
// 128 MiB f32 logits round-trip. GEMM core/schedule identical to round 6.
// ---------------------------------------------------------------------------

typedef __bf16 bf16x8 __attribute__((ext_vector_type(8)));
typedef __bf16 bf16x4 __attribute__((ext_vector_type(4)));
typedef float  f32x4  __attribute__((ext_vector_type(4)));

__device__ __forceinline__ void gload_lds16(const void* g, void* l) {
  __builtin_amdgcn_global_load_lds(
      (__attribute__((address_space(1))) void*)(g),
      (__attribute__((address_space(3))) void*)(uintptr_t)(l),
      16, 0, 0);
}

// Read 4 MFMA A/B fragments (16x16x32) from a 256x32 K-half region.
// Region layout: elem = row*32 + granule*8, granule pre-swizzled by
// g ^ ((row>>1)&3).
__device__ __forceinline__ void ldfrag4(bf16x8 (&f)[4], const __bf16* reg_,
                                        int rbase, int fm, int gq) {
#pragma unroll
  for (int i = 0; i < 4; ++i) {
    const int r = rbase + i * 16 + fm;
    f[i] = *(const bf16x8*)(reg_ + r * 32 + ((gq ^ ((r >> 1) & 3)) << 3));
  }
}

// Stage one 256x32 K-half (16 KiB): 2 global_load_lds per thread.
__device__ __forceinline__ void stage16(const __bf16* src, __bf16* dst,
                                        size_t rowstride, int wave, int lane) {
#pragma unroll
  for (int i = 0; i < 2; ++i) {
    const int chunk = wave * 2 + i;            // 16 chunks of 16 rows
    const int row = chunk * 16 + (lane >> 2);
    const int gg = (lane & 3) ^ ((row >> 1) & 3);   // pre-swizzled source
    gload_lds16(src + (size_t)row * rowstride + (gg << 3), dst + chunk * 512);
  }
}

template <int MH>
__device__ __forceinline__ void mfma16(f32x4 (&acc)[8][4], const bf16x8 (&a)[4],
                                       const bf16x8 (&b)[4]) {
#pragma unroll
  for (int mi = 0; mi < 4; ++mi)
#pragma unroll
    for (int nj = 0; nj < 4; ++nj)
      acc[MH * 4 + mi][nj] = __builtin_amdgcn_mfma_f32_16x16x32_bf16(
          a[mi], b[nj], acc[MH * 4 + mi][nj], 0, 0, 0);
}

#define PHASE_MID()                       \
  __builtin_amdgcn_sched_barrier(0);      \
  __builtin_amdgcn_s_barrier();           \
  __builtin_amdgcn_s_setprio(1)

#define PHASE_END()                       \
  __builtin_amdgcn_s_setprio(0);          \
  __builtin_amdgcn_sched_barrier(0);      \
  __builtin_amdgcn_s_barrier()

// ---------------------------------------------------------------------------
// One 256x256 output tile, NT: C[m,n] = sum_k A[m,k]*B[n,k], K mult of 128.
// 8-phase double-buffered schedule, counted vmcnt(6) at phases 4/8 only.
// Chainable back-to-back (FIFO vmcnt covers prior epilogue store drain).
// EPI: 0 = f32 out (scaled), 1 = bf16 out,
//      2 = QK-softmax stats: scale acc, store bf16(x - rowmax_tile) to Cp,
//          side[(row)*8+bx] = (m_tile, sum exp(stored)).  Uses LDS scratch
//          after the main loop (quiescent), barriers before return.
// ---------------------------------------------------------------------------
template <int EPI>
__device__ __forceinline__ void tile_gemm(
    const __bf16* __restrict__ Aa, const __bf16* __restrict__ Ba,
    void* __restrict__ Cp, size_t cbase, int N, int K, float scale,
    __bf16* lds, int wave, int lane, int wm, int wn, int fm, int gq,
    float* side, int sidebase) {
  __bf16* const As_ = lds;
  __bf16* const Bs_ = lds + 32768;
#define AREG(p, h) (As_ + (p) * 16384 + (h) * 8192)
#define BREG(p, h) (Bs_ + (p) * 16384 + (h) * 8192)

  f32x4 acc[8][4] = {};
  bf16x8 a[4], b[4];

  // ---- prologue: tile0 fully + 3 halves of tile1 ----
  stage16(Ba + 0,  BREG(0, 0), K, wave, lane);
  stage16(Aa + 0,  AREG(0, 0), K, wave, lane);
  stage16(Ba + 32, BREG(0, 1), K, wave, lane);
  stage16(Aa + 32, AREG(0, 1), K, wave, lane);
  asm volatile("s_waitcnt vmcnt(4)" ::: "memory");
  stage16(Ba + 64, BREG(1, 0), K, wave, lane);
  stage16(Aa + 64, AREG(1, 0), K, wave, lane);
  stage16(Ba + 96, BREG(1, 1), K, wave, lane);
  asm volatile("s_waitcnt vmcnt(6)" ::: "memory");
  __builtin_amdgcn_s_barrier();

  const int niter = K >> 7;   // 2 K-tiles (BK=64) per iteration
  for (int it = 0; it < niter; ++it) {
    const int kt = it << 7;
    const bool s2 = (kt + 128) < K;   // tiles t+2 / t+3 exist (block-uniform)

    // ---- phase 1: buf0 (mh0,kh0); stage (t+1).A-kh1 ----
    ldfrag4(a, AREG(0, 0), wm, fm, gq);
    ldfrag4(b, BREG(0, 0), wn, fm, gq);
    stage16(Aa + kt + 96, AREG(1, 1), K, wave, lane);
    PHASE_MID();
    mfma16<0>(acc, a, b);
    PHASE_END();

    // ---- phase 2: (mh1,kh0); stage (t+2).B-kh0 ----
    ldfrag4(a, AREG(0, 0), wm + 64, fm, gq);
    if (s2) stage16(Ba + kt + 128, BREG(0, 0), K, wave, lane);
    PHASE_MID();
    mfma16<1>(acc, a, b);
    PHASE_END();

    // ---- phase 3: (mh0,kh1); stage (t+2).A-kh0 ----
    ldfrag4(a, AREG(0, 1), wm, fm, gq);
    ldfrag4(b, BREG(0, 1), wn, fm, gq);
    if (s2) stage16(Aa + kt + 128, AREG(0, 0), K, wave, lane);
    PHASE_MID();
    mfma16<0>(acc, a, b);
    PHASE_END();

    // ---- phase 4: (mh1,kh1); stage (t+2).B-kh1; counted vmcnt ----
    ldfrag4(a, AREG(0, 1), wm + 64, fm, gq);
    if (s2) stage16(Ba + kt + 160, BREG(0, 1), K, wave, lane);
    PHASE_MID();
    mfma16<1>(acc, a, b);
    __builtin_amdgcn_s_setprio(0);
    __builtin_amdgcn_sched_barrier(0);
    if (s2) { asm volatile("s_waitcnt vmcnt(6)" ::: "memory"); }
    else    { asm volatile("s_waitcnt vmcnt(0)" ::: "memory"); }
    __builtin_amdgcn_s_barrier();

    // ---- phase 5: buf1 (mh0,kh0); stage (t+2).A-kh1 ----
    ldfrag4(a, AREG(1, 0), wm, fm, gq);
    ldfrag4(b, BREG(1, 0), wn, fm, gq);
    if (s2) stage16(Aa + kt + 160, AREG(0, 1), K, wave, lane);
    PHASE_MID();
    mfma16<0>(acc, a, b);
    PHASE_END();

    // ---- phase 6: (mh1,kh0); stage (t+3).B-kh0 ----
    ldfrag4(a, AREG(1, 0), wm + 64, fm, gq);
    if (s2) stage16(Ba + kt + 192, BREG(1, 0), K, wave, lane);
    PHASE_MID();
    mfma16<1>(acc, a, b);
    PHASE_END();

    // ---- phase 7: (mh0,kh1); stage (t+3).A-kh0 ----
    ldfrag4(a, AREG(1, 1), wm, fm, gq);
    ldfrag4(b, BREG(1, 1), wn, fm, gq);
    if (s2) stage16(Aa + kt + 192, AREG(1, 0), K, wave, lane);
    PHASE_MID();
    mfma16<0>(acc, a, b);
    PHASE_END();

    // ---- phase 8: (mh1,kh1); stage (t+3).B-kh1; counted vmcnt ----
    ldfrag4(a, AREG(1, 1), wm + 64, fm, gq);
    if (s2) stage16(Ba + kt + 224, BREG(1, 1), K, wave, lane);
    PHASE_MID();
    mfma16<1>(acc, a, b);
    __builtin_amdgcn_s_setprio(0);
    __builtin_amdgcn_sched_barrier(0);
    if (s2) { asm volatile("s_waitcnt vmcnt(6)" ::: "memory"); }
    __builtin_amdgcn_s_barrier();
  }

  // ---- epilogue: C/D layout col=lane&15, row=(lane>>4)*4+reg ----
  const int col   = lane & 15;
  const int rquad = (lane >> 4) * 4;

  if constexpr (EPI != 2) {
#pragma unroll
    for (int mi = 0; mi < 8; ++mi) {
#pragma unroll
      for (int r = 0; r < 4; ++r) {
        const size_t roff = (size_t)(wm + mi * 16 + rquad + r) * (size_t)N;
#pragma unroll
        for (int nj = 0; nj < 4; ++nj) {
          const size_t cidx = cbase + roff + wn + nj * 16 + col;
          if constexpr (EPI == 1) {
            ((__bf16*)Cp)[cidx] = (__bf16)acc[mi][nj][r];
          } else {
            ((float*)Cp)[cidx] = acc[mi][nj][r] * scale;
          }
        }
      }
    }
  } else {
    // ---- QK softmax-stats epilogue (LDS quiescent after final barrier) ----
    const int tid = (wave << 6) | lane;
    float* red  = (float*)lds;          // [4][256] partials (max, then sum)
    float* mrow = red + 1024;           // [256] combined tile row-max
    // scale logits once
#pragma unroll
    for (int mi = 0; mi < 8; ++mi)
#pragma unroll
      for (int nj = 0; nj < 4; ++nj) acc[mi][nj] = acc[mi][nj] * scale;
    // pass 1: per-row max partials (reduce nj, then 16 col-lanes)
#pragma unroll
    for (int mi = 0; mi < 8; ++mi) {
#pragma unroll
      for (int r = 0; r < 4; ++r) {
        float vm = fmaxf(fmaxf(acc[mi][0][r], acc[mi][1][r]),
                         fmaxf(acc[mi][2][r], acc[mi][3][r]));
#pragma unroll
        for (int off = 8; off > 0; off >>= 1)
          vm = fmaxf(vm, __shfl_xor(vm, off));
        if ((lane & 15) == 0)
          red[(wave & 3) * 256 + wm + mi * 16 + rquad + r] = vm;
      }
    }
    __syncthreads();
    if (tid < 256)
      mrow[tid] = fmaxf(fmaxf(red[tid], red[256 + tid]),
                        fmaxf(red[512 + tid], red[768 + tid]));
    __syncthreads();
    // pass 2: store bf16(x - m_tile), accumulate sum of exp(stored)
#pragma unroll
    for (int mi = 0; mi < 8; ++mi) {
#pragma unroll
      for (int r = 0; r < 4; ++r) {
        const int rloc = wm + mi * 16 + rquad + r;
        const float m = mrow[rloc];
        const size_t roff = (size_t)rloc * (size_t)N;
        float ss = 0.f;
#pragma unroll
        for (int nj = 0; nj < 4; ++nj) {
          const __bf16 hb = (__bf16)(acc[mi][nj][r] - m);
          ((__bf16*)Cp)[cbase + roff + wn + nj * 16 + col] = hb;
          ss += __expf((float)hb);
        }
#pragma unroll
        for (int off = 8; off > 0; off >>= 1) ss += __shfl_xor(ss, off);
        if ((lane & 15) == 0) red[(wave & 3) * 256 + rloc] = ss;
      }
    }
    __syncthreads();
    if (tid < 256) {
      const float s =
          red[tid] + red[256 + tid] + red[512 + tid] + red[768 + tid];
      const size_t si = (size_t)(sidebase + tid * 8) * 2;
      side[si]     = mrow[tid];
      side[si + 1] = s;
    }
    __syncthreads();  // protect LDS scratch before next chained prologue
  }
#undef AREG
#undef BREG
}

// ---------------------------------------------------------------------------
// proj_all: 256 blocks, 3 chained tiles each.
// ---------------------------------------------------------------------------
__global__ __launch_bounds__(512, 2)
void proj_all(const __bf16* __restrict__ rnnb, const __bf16* __restrict__ Ltb,
              const __bf16* __restrict__ Wt, const __bf16* __restrict__ k0t,
              const __bf16* __restrict__ k1t, __bf16* __restrict__ WQ,
              __bf16* __restrict__ WK, __bf16* __restrict__ WVt) {
  __shared__ __bf16 lds[65536];
  const int tid = threadIdx.x, wave = tid >> 6, lane = tid & 63;
  const int wm = (wave >> 2) * 128, wn = (wave & 3) * 64;
  const int fm = lane & 15, gq = lane >> 4;
  const int d = blockIdx.x, x = d & 7, s = d >> 3;

  {  // projections: 64 by-panels x 4 bx; XCD x owns by in [8x, 8x+8)
    const int bx = s & 3, by = x * 8 + (s >> 2);
    const size_t ao = (size_t)by * 256 * 1024;
    const size_t bo = (size_t)bx * 256 * 1024;
    const size_t cb = (size_t)by * 256 * 1024 + (size_t)bx * 256;
    tile_gemm<1>(rnnb + ao, Wt + bo, WQ, cb, 1024, 1024, 1.0f,
                 lds, wave, lane, wm, wn, fm, gq, nullptr, 0);
    tile_gemm<1>(Ltb + ao, k0t + bo, WK, cb, 1024, 1024, 1.0f,
                 lds, wave, lane, wm, wn, fm, gq, nullptr, 0);
  }
  {  // WV: batch x on XCD x; by = e-tile (0..3), bx = k-tile (0..7)
    const int by = s >> 3, bx = s & 7;
    tile_gemm<1>(k1t + (size_t)by * 256 * 1024,
                 Ltb + (size_t)x * 2048 * 1024 + (size_t)bx * 256 * 1024,
                 WVt,
                 (size_t)x * 1024 * 2048 + (size_t)by * 256 * 2048 +
                     (size_t)bx * 256,
                 2048, 1024, 1.0f, lds, wave, lane, wm, wn, fm, gq,
                 nullptr, 0);
  }
}

// ---------------------------------------------------------------------------
// qk_sm: 256 blocks, 2 chained tiles (same B-panel). Stores tile-max-relative
// bf16 logits into Pb + (m,s) stats per (row, bx) into side.
// ---------------------------------------------------------------------------
__global__ __launch_bounds__(512, 2)
void qk_sm(const __bf16* __restrict__ WQ, const __bf16* __restrict__ WK,
           __bf16* __restrict__ Pb, float* __restrict__ side) {
  __shared__ __bf16 lds[65536];
  const int tid = threadIdx.x, wave = tid >> 6, lane = tid & 63;
  const int wm = (wave >> 2) * 128, wn = (wave & 3) * 64;
  const int fm = lane & 15, gq = lane >> 4;
  const int d = blockIdx.x, x = d & 7, s = d >> 3;
  const int by = s >> 3, bx = s & 7;   // by 0..3 (then +4), bx 0..7

  const __bf16* Qb = WQ + (size_t)x * 2048 * 1024;
  const __bf16* Kb = WK + (size_t)x * 2048 * 1024 + (size_t)bx * 256 * 1024;
  const size_t cb0 = (size_t)x * 2048 * 2048 + (size_t)bx * 256;

  tile_gemm<2>(Qb + (size_t)by * 256 * 1024, Kb, Pb,
               cb0 + (size_t)by * 256 * 2048, 2048, 1024, 0.125f,
               lds, wave, lane, wm, wn, fm, gq,
               side, (x * 2048 + by * 256) * 8 + bx);
  tile_gemm<2>(Qb + (size_t)(by + 4) * 256 * 1024, Kb, Pb,
               cb0 + (size_t)(by + 4) * 256 * 2048, 2048, 1024, 0.125f,
               lds, wave, lane, wm, wn, fm, gq,
               side, (x * 2048 + (by + 4) * 256) * 8 + bx);
}

// ---------------------------------------------------------------------------
// sm_finalize: one block per row. Combine 8 (m,s) stats, write f32 weights
// and normalized bf16 Pb in place.  w = exp(stored) * exp(m_t - m_f) / s_f.
// ---------------------------------------------------------------------------
__global__ __launch_bounds__(256)
void sm_finalize(const float* __restrict__ side, __bf16* __restrict__ Pb,
                 float* __restrict__ wts) {
  const size_t row = blockIdx.x;          // b*2048 + r
  const int t = threadIdx.x;
  __shared__ float mt[8], st[8], fac[8];
  if (t < 8) {
    mt[t] = side[(row * 8 + t) * 2];
    st[t] = side[(row * 8 + t) * 2 + 1];
  }
  __syncthreads();
  if (t < 8) {
    float mf = mt[0];
#pragma unroll
    for (int i = 1; i < 8; ++i) mf = fmaxf(mf, mt[i]);
    float sf = 0.f;
#pragma unroll
    for (int i = 0; i < 8; ++i) sf += st[i] * __expf(mt[i] - mf);
    fac[t] = __expf(mt[t] - mf) / sf;
  }
  __syncthreads();
  __bf16* pb = Pb + row * 2048 + t * 8;
  float*  w  = wts + row * 2048 + t * 8;
  bf16x8 v = *(const bf16x8*)pb;
  const float f = fac[t >> 5];   // cols t*8..t*8+7 all in tile (t*8)>>8
  float wv[8];
#pragma unroll
  for (int i = 0; i < 8; ++i) wv[i] = __expf((float)v[i]) * f;
  float4 w0 = {wv[0], wv[1], wv[2], wv[3]};
  float4 w1 = {wv[4], wv[5], wv[6], wv[7]};
  ((float4*)w)[0] = w0;
  ((float4*)w)[1] = w1;
  bf16x8 pv;
#pragma unroll
  for (int i = 0; i < 8; ++i) pv[i] = (__bf16)wv[i];
  *(bf16x8*)pb = pv;
}

// ---------------------------------------------------------------------------
// pv1: 256 blocks, 1 tile. ctx[b][q][e] = Pb[b][q,:] . WVt[b][e,:]
// ---------------------------------------------------------------------------
__global__ __launch_bounds__(512, 2)
void pv1(const __bf16* __restrict__ Pb, const __bf16* __restrict__ WVt,
         float* __restrict__ ctx) {
  __shared__ __bf16 lds[65536];
  const int tid = threadIdx.x, wave = tid >> 6, lane = tid & 63;
  const int wm = (wave >> 2) * 128, wn = (wave & 3) * 64;
  const int fm = lane & 15, gq = lane >> 4;
  const int d = blockIdx.x, x = d & 7, s = d >> 3;
  const int by = s >> 2, bx = s & 3;   // by 0..7 (q-tile), bx 0..3 (e-tile)

  tile_gemm<0>(Pb + (size_t)x * 2048 * 2048 + (size_t)by * 256 * 2048,
               WVt + (size_t)x * 1024 * 2048 + (size_t)bx * 256 * 2048,
               ctx,
               (size_t)x * 2048 * 1024 + (size_t)by * 256 * 1024 +
                   (size_t)bx * 256,
               1024, 2048, 1.0f, lds, wave, lane, wm, wn, fm, gq,
               nullptr, 0);
}

// ---------------------------------------------------------------------------
// cvt+transpose 1024x1024 f32 -> bf16 (out[n,d] = in[d,n]); z selects matrix
// ---------------------------------------------------------------------------
__global__ __launch_bounds__(256)
void cvt_transpose(const float* __restrict__ s0, const float* __restrict__ s1,
                   const float* __restrict__ s2, __bf16* __restrict__ d0,
                   __bf16* __restrict__ d1, __bf16* __restrict__ d2) {
  const float* s = blockIdx.z == 0 ? s0 : (blockIdx.z == 1 ? s1 : s2);
  __bf16* d      = blockIdx.z == 0 ? d0 : (blockIdx.z == 1 ? d1 : d2);
  __shared__ float tile[32][33];
  const int x  = blockIdx.x * 32 + threadIdx.x;
  const int y0 = blockIdx.y * 32;
  for (int j = threadIdx.y; j < 32; j += 8)
    tile[j][threadIdx.x] = s[(size_t)(y0 + j) * 1024 + x];
  __syncthreads();
  const int x2 = y0 + threadIdx.x;
  const int y2 = blockIdx.x * 32;
  for (int j = threadIdx.y; j < 32; j += 8)
    d[(size_t)(y2 + j) * 1024 + x2] = (__bf16)tile[threadIdx.x][j];
}

// ---------------------------------------------------------------------------
// elementwise f32 -> bf16, Lt and rnn_ht
// ---------------------------------------------------------------------------
__global__ __launch_bounds__(256)
void cvt_bf16(const float* __restrict__ s0, __bf16* __restrict__ d0,
              const float* __restrict__ s1, __bf16* __restrict__ d1) {
  const float* s = blockIdx.z ? s1 : s0;
  __bf16* d      = blockIdx.z ? d1 : d0;
  const size_t i = ((size_t)blockIdx.x * 256 + threadIdx.x) * 4;
  float4 f = *(const float4*)(s + i);
  bf16x4 h = {(__bf16)f.x, (__bf16)f.y, (__bf16)f.z, (__bf16)f.w};
  *(bf16x4*)(d + i) = h;
}

// ---------------------------------------------------------------------------
extern "C" void kernel_launch(void* const* d_in, const int* in_sizes, int n_in,
                              void* d_out, int out_size, void* d_ws,
                              size_t ws_size, hipStream_t stream) {
  const float* Lt  = (const float*)d_in[0];  // [8,2048,1024]
  const float* rnn = (const float*)d_in[1];  // [8,2048,1024]
  const float* ker = (const float*)d_in[2];  // [2,1024,1024]
  const float* W   = (const float*)d_in[3];  // [1024,1024]

  float* ctx = (float*)d_out;                // [8,2048,1024]
  float* wts = ctx + (size_t)16777216;       // [8,2048,2048]

  __bf16* ws   = (__bf16*)d_ws;
  __bf16* Wt   = ws;                         // [1024,1024]  (n,d)   2 MiB
  __bf16* k0t  = Wt + (1u << 20);            // [1024,1024]          2 MiB
  __bf16* k1t  = k0t + (1u << 20);           // [1024,1024]          2 MiB
  __bf16* WQ   = k1t + (1u << 20);           // [8*2048,1024]       32 MiB
  __bf16* WK   = WQ + (16u << 20);           // [8*2048,1024]       32 MiB
  __bf16* WVt  = WK + (16u << 20);           // [8][1024][2048]     32 MiB
  __bf16* Ltb  = WVt + (16u << 20);          // [8,2048,1024] bf16  32 MiB
  __bf16* rnnb = Ltb + (16u << 20);          // [8,2048,1024] bf16  32 MiB
  __bf16* Pb = Ltb;        // Pb overlaps Ltb+rnnb (dead after proj/qk) 64 MiB
  float* side = (float*)Wt;  // stats [8*2048][8][2] f32 = 1 MiB, Wt dead

  // 1) transpose + cvt the three weight matrices
  cvt_transpose<<<dim3(32, 32, 3), dim3(32, 8), 0, stream>>>(
      W, ker, ker + (1u << 20), Wt, k0t, k1t);

  // 1b) cvt Lt and rnn_ht to bf16
  cvt_bf16<<<dim3(16384, 1, 2), 256, 0, stream>>>(Lt, Ltb, rnn, rnnb);

  // 2) WQ, WK, WVt in one launch (3 chained tiles per block)
  proj_all<<<256, 512, 0, stream>>>(rnnb, Ltb, Wt, k0t, k1t, WQ, WK, WVt);

  // 3) QK + softmax stats (2 chained tiles per block); no f32 logits traffic
  qk_sm<<<256, 512, 0, stream>>>(WQ, WK, Pb, side);

  // 4) combine stats, write f32 weights + normalized bf16 Pb in place
  sm_finalize<<<16384, 256, 0, stream>>>(side, Pb, wts);

  // 5) ctx[b,q,e] = sum_k P[b,q,k] * WVt[b,e,k]
  pv1<<<256, 512, 0, stream>>>(Pb, WVt, ctx);
}

// Round 6
// 570.212 us; speedup vs baseline: 1.0499x; 1.0499x over previous
//
#include <hip/hip_runtime.h>

// ---------------------------------------------------------------------------
// ScaledDotProductAttention: B=8, Sq=Sk=2048, D=E=1024, f32 in/out.
// Round 8: revert split-softmax (r7 regressed); round-6 dataflow.
//   KEY CHANGE: removed all sched_barrier(0) from the 8-phase GEMM loop
//   (m141-class order-pinning suspect; the verified m201 template has none).
//   Phases are now: [ds_read | stage] barrier; setprio; MFMA; setprio; barrier
//   with counted vmcnt(6) only at phases 4/8 (never 0 in steady state).
//   Also: cvt_transpose + cvt_bf16 merged into one launch (cvt_all).
// ---------------------------------------------------------------------------

typedef __bf16 bf16x8 __attribute__((ext_vector_type(8)));
typedef __bf16 bf16x4 __attribute__((ext_vector_type(4)));
typedef float  f32x4  __attribute__((ext_vector_type(4)));

__device__ __forceinline__ void gload_lds16(const void* g, void* l) {
  __builtin_amdgcn_global_load_lds(
      (__attribute__((address_space(1))) void*)(g),
      (__attribute__((address_space(3))) void*)(uintptr_t)(l),
      16, 0, 0);
}

// Read 4 MFMA A/B fragments (16x16x32) from a 256x32 K-half region.
// Region layout: elem = row*32 + granule*8, granule pre-swizzled by
// g ^ ((row>>1)&3).
__device__ __forceinline__ void ldfrag4(bf16x8 (&f)[4], const __bf16* reg_,
                                        int rbase, int fm, int gq) {
#pragma unroll
  for (int i = 0; i < 4; ++i) {
    const int r = rbase + i * 16 + fm;
    f[i] = *(const bf16x8*)(reg_ + r * 32 + ((gq ^ ((r >> 1) & 3)) << 3));
  }
}

// Stage one 256x32 K-half (16 KiB): 2 global_load_lds per thread.
__device__ __forceinline__ void stage16(const __bf16* src, __bf16* dst,
                                        size_t rowstride, int wave, int lane) {
#pragma unroll
  for (int i = 0; i < 2; ++i) {
    const int chunk = wave * 2 + i;            // 16 chunks of 16 rows
    const int row = chunk * 16 + (lane >> 2);
    const int gg = (lane & 3) ^ ((row >> 1) & 3);   // pre-swizzled source
    gload_lds16(src + (size_t)row * rowstride + (gg << 3), dst + chunk * 512);
  }
}

template <int MH>
__device__ __forceinline__ void mfma16(f32x4 (&acc)[8][4], const bf16x8 (&a)[4],
                                       const bf16x8 (&b)[4]) {
#pragma unroll
  for (int mi = 0; mi < 4; ++mi)
#pragma unroll
    for (int nj = 0; nj < 4; ++nj)
      acc[MH * 4 + mi][nj] = __builtin_amdgcn_mfma_f32_16x16x32_bf16(
          a[mi], b[nj], acc[MH * 4 + mi][nj], 0, 0, 0);
}

// No sched_barrier(0) here: let the compiler pipeline across phases (m141).
#define PHASE_MID()                       \
  __builtin_amdgcn_s_barrier();           \
  __builtin_amdgcn_s_setprio(1)

#define PHASE_END()                       \
  __builtin_amdgcn_s_setprio(0);          \
  __builtin_amdgcn_s_barrier()

// ---------------------------------------------------------------------------
// One 256x256 output tile, NT: C[m,n] = sum_k A[m,k]*B[n,k], K mult of 128.
// 8-phase double-buffered schedule, counted vmcnt(6) at phases 4/8 only.
// Chainable back-to-back.
// ---------------------------------------------------------------------------
template <bool OUTBF16>
__device__ __forceinline__ void tile_gemm(
    const __bf16* __restrict__ Aa, const __bf16* __restrict__ Ba,
    void* __restrict__ Cp, size_t cbase, int N, int K, float scale,
    __bf16* lds, int wave, int lane, int wm, int wn, int fm, int gq) {
  __bf16* const As_ = lds;
  __bf16* const Bs_ = lds + 32768;
#define AREG(p, h) (As_ + (p) * 16384 + (h) * 8192)
#define BREG(p, h) (Bs_ + (p) * 16384 + (h) * 8192)

  f32x4 acc[8][4] = {};
  bf16x8 a[4], b[4];

  // ---- prologue: tile0 fully + 3 halves of tile1 ----
  stage16(Ba + 0,  BREG(0, 0), K, wave, lane);
  stage16(Aa + 0,  AREG(0, 0), K, wave, lane);
  stage16(Ba + 32, BREG(0, 1), K, wave, lane);
  stage16(Aa + 32, AREG(0, 1), K, wave, lane);
  asm volatile("s_waitcnt vmcnt(4)" ::: "memory");
  stage16(Ba + 64, BREG(1, 0), K, wave, lane);
  stage16(Aa + 64, AREG(1, 0), K, wave, lane);
  stage16(Ba + 96, BREG(1, 1), K, wave, lane);
  asm volatile("s_waitcnt vmcnt(6)" ::: "memory");
  __builtin_amdgcn_s_barrier();

  const int niter = K >> 7;   // 2 K-tiles (BK=64) per iteration
  for (int it = 0; it < niter; ++it) {
    const int kt = it << 7;
    const bool s2 = (kt + 128) < K;   // tiles t+2 / t+3 exist (block-uniform)

    // ---- phase 1: buf0 (mh0,kh0); stage this-iter buf1.A-kh1 ----
    ldfrag4(a, AREG(0, 0), wm, fm, gq);
    ldfrag4(b, BREG(0, 0), wn, fm, gq);
    stage16(Aa + kt + 96, AREG(1, 1), K, wave, lane);
    PHASE_MID();
    mfma16<0>(acc, a, b);
    PHASE_END();

    // ---- phase 2: (mh1,kh0); stage (t+2).B-kh0 ----
    ldfrag4(a, AREG(0, 0), wm + 64, fm, gq);
    if (s2) stage16(Ba + kt + 128, BREG(0, 0), K, wave, lane);
    PHASE_MID();
    mfma16<1>(acc, a, b);
    PHASE_END();

    // ---- phase 3: (mh0,kh1); stage (t+2).A-kh0 ----
    ldfrag4(a, AREG(0, 1), wm, fm, gq);
    ldfrag4(b, BREG(0, 1), wn, fm, gq);
    if (s2) stage16(Aa + kt + 128, AREG(0, 0), K, wave, lane);
    PHASE_MID();
    mfma16<0>(acc, a, b);
    PHASE_END();

    // ---- phase 4: (mh1,kh1); stage (t+2).B-kh1; counted vmcnt ----
    ldfrag4(a, AREG(0, 1), wm + 64, fm, gq);
    if (s2) stage16(Ba + kt + 160, BREG(0, 1), K, wave, lane);
    PHASE_MID();
    mfma16<1>(acc, a, b);
    __builtin_amdgcn_s_setprio(0);
    if (s2) { asm volatile("s_waitcnt vmcnt(6)" ::: "memory"); }
    else    { asm volatile("s_waitcnt vmcnt(0)" ::: "memory"); }
    __builtin_amdgcn_s_barrier();

    // ---- phase 5: buf1 (mh0,kh0); stage (t+2).A-kh1 ----
    ldfrag4(a, AREG(1, 0), wm, fm, gq);
    ldfrag4(b, BREG(1, 0), wn, fm, gq);
    if (s2) stage16(Aa + kt + 160, AREG(0, 1), K, wave, lane);
    PHASE_MID();
    mfma16<0>(acc, a, b);
    PHASE_END();

    // ---- phase 6: (mh1,kh0); stage (t+3).B-kh0 ----
    ldfrag4(a, AREG(1, 0), wm + 64, fm, gq);
    if (s2) stage16(Ba + kt + 192, BREG(1, 0), K, wave, lane);
    PHASE_MID();
    mfma16<1>(acc, a, b);
    PHASE_END();

    // ---- phase 7: (mh0,kh1); stage (t+3).A-kh0 ----
    ldfrag4(a, AREG(1, 1), wm, fm, gq);
    ldfrag4(b, BREG(1, 1), wn, fm, gq);
    if (s2) stage16(Aa + kt + 192, AREG(1, 0), K, wave, lane);
    PHASE_MID();
    mfma16<0>(acc, a, b);
    PHASE_END();

    // ---- phase 8: (mh1,kh1); stage (t+3).B-kh1; counted vmcnt ----
    ldfrag4(a, AREG(1, 1), wm + 64, fm, gq);
    if (s2) stage16(Ba + kt + 224, BREG(1, 1), K, wave, lane);
    PHASE_MID();
    mfma16<1>(acc, a, b);
    __builtin_amdgcn_s_setprio(0);
    if (s2) { asm volatile("s_waitcnt vmcnt(6)" ::: "memory"); }
    __builtin_amdgcn_s_barrier();
  }

  // ---- epilogue: C/D layout col=lane&15, row=(lane>>4)*4+reg ----
  const int col   = lane & 15;
  const int rquad = (lane >> 4) * 4;
#pragma unroll
  for (int mi = 0; mi < 8; ++mi) {
#pragma unroll
    for (int r = 0; r < 4; ++r) {
      const size_t roff = (size_t)(wm + mi * 16 + rquad + r) * (size_t)N;
#pragma unroll
      for (int nj = 0; nj < 4; ++nj) {
        const size_t cidx = cbase + roff + wn + nj * 16 + col;
        if constexpr (OUTBF16) {
          ((__bf16*)Cp)[cidx] = (__bf16)acc[mi][nj][r];
        } else {
          ((float*)Cp)[cidx] = acc[mi][nj][r] * scale;
        }
      }
    }
  }
#undef AREG
#undef BREG
}

// ---------------------------------------------------------------------------
// proj_all: 256 blocks, 3 chained tiles each.
// ---------------------------------------------------------------------------
__global__ __launch_bounds__(512, 2)
void proj_all(const __bf16* __restrict__ rnnb, const __bf16* __restrict__ Ltb,
              const __bf16* __restrict__ Wt, const __bf16* __restrict__ k0t,
              const __bf16* __restrict__ k1t, __bf16* __restrict__ WQ,
              __bf16* __restrict__ WK, __bf16* __restrict__ WVt) {
  __shared__ __bf16 lds[65536];
  const int tid = threadIdx.x, wave = tid >> 6, lane = tid & 63;
  const int wm = (wave >> 2) * 128, wn = (wave & 3) * 64;
  const int fm = lane & 15, gq = lane >> 4;
  const int d = blockIdx.x, x = d & 7, s = d >> 3;

  {  // projections: 64 by-panels x 4 bx; XCD x owns by in [8x, 8x+8)
    const int bx = s & 3, by = x * 8 + (s >> 2);
    const size_t ao = (size_t)by * 256 * 1024;
    const size_t bo = (size_t)bx * 256 * 1024;
    const size_t cb = (size_t)by * 256 * 1024 + (size_t)bx * 256;
    tile_gemm<true>(rnnb + ao, Wt + bo, WQ, cb, 1024, 1024, 1.0f,
                    lds, wave, lane, wm, wn, fm, gq);
    tile_gemm<true>(Ltb + ao, k0t + bo, WK, cb, 1024, 1024, 1.0f,
                    lds, wave, lane, wm, wn, fm, gq);
  }
  {  // WV: batch x on XCD x; by = e-tile (0..3), bx = k-tile (0..7)
    const int by = s >> 3, bx = s & 7;
    tile_gemm<true>(k1t + (size_t)by * 256 * 1024,
                    Ltb + (size_t)x * 2048 * 1024 + (size_t)bx * 256 * 1024,
                    WVt,
                    (size_t)x * 1024 * 2048 + (size_t)by * 256 * 2048 +
                        (size_t)bx * 256,
                    2048, 1024, 1.0f, lds, wave, lane, wm, wn, fm, gq);
  }
}

// ---------------------------------------------------------------------------
// qk2: 256 blocks, 2 chained tiles (same B-panel, L2-hot on 2nd tile).
// ---------------------------------------------------------------------------
__global__ __launch_bounds__(512, 2)
void qk2(const __bf16* __restrict__ WQ, const __bf16* __restrict__ WK,
         float* __restrict__ wts) {
  __shared__ __bf16 lds[65536];
  const int tid = threadIdx.x, wave = tid >> 6, lane = tid & 63;
  const int wm = (wave >> 2) * 128, wn = (wave & 3) * 64;
  const int fm = lane & 15, gq = lane >> 4;
  const int d = blockIdx.x, x = d & 7, s = d >> 3;
  const int by = s >> 3, bx = s & 7;   // by 0..3 (then +4), bx 0..7

  const __bf16* Qb = WQ + (size_t)x * 2048 * 1024;
  const __bf16* Kb = WK + (size_t)x * 2048 * 1024 + (size_t)bx * 256 * 1024;
  const size_t cb0 = (size_t)x * 2048 * 2048 + (size_t)bx * 256;

  tile_gemm<false>(Qb + (size_t)by * 256 * 1024, Kb, wts,
                   cb0 + (size_t)by * 256 * 2048, 2048, 1024, 0.125f,
                   lds, wave, lane, wm, wn, fm, gq);
  tile_gemm<false>(Qb + (size_t)(by + 4) * 256 * 1024, Kb, wts,
                   cb0 + (size_t)(by + 4) * 256 * 2048, 2048, 1024, 0.125f,
                   lds, wave, lane, wm, wn, fm, gq);
}

// ---------------------------------------------------------------------------
// pv1: 256 blocks, 1 tile. ctx[b][q][e] = Pb[b][q,:] . WVt[b][e,:]
// ---------------------------------------------------------------------------
__global__ __launch_bounds__(512, 2)
void pv1(const __bf16* __restrict__ Pb, const __bf16* __restrict__ WVt,
         float* __restrict__ ctx) {
  __shared__ __bf16 lds[65536];
  const int tid = threadIdx.x, wave = tid >> 6, lane = tid & 63;
  const int wm = (wave >> 2) * 128, wn = (wave & 3) * 64;
  const int fm = lane & 15, gq = lane >> 4;
  const int d = blockIdx.x, x = d & 7, s = d >> 3;
  const int by = s >> 2, bx = s & 3;   // by 0..7 (q-tile), bx 0..3 (e-tile)

  tile_gemm<false>(Pb + (size_t)x * 2048 * 2048 + (size_t)by * 256 * 2048,
                   WVt + (size_t)x * 1024 * 2048 + (size_t)bx * 256 * 2048,
                   ctx,
                   (size_t)x * 2048 * 1024 + (size_t)by * 256 * 1024 +
                       (size_t)bx * 256,
                   1024, 2048, 1.0f, lds, wave, lane, wm, wn, fm, gq);
}

// ---------------------------------------------------------------------------
// cvt_all: merged weight-transpose (blocks 0..3071) + flat f32->bf16 cvt of
// Lt and rnn (blocks 3072..36863).  256 threads.
// ---------------------------------------------------------------------------
__global__ __launch_bounds__(256)
void cvt_all(const float* __restrict__ W, const float* __restrict__ ker,
             __bf16* __restrict__ Wt, __bf16* __restrict__ k0t,
             __bf16* __restrict__ k1t,
             const float* __restrict__ Lt, __bf16* __restrict__ Ltb,
             const float* __restrict__ rnn, __bf16* __restrict__ rnnb) {
  const int d = blockIdx.x;
  const int t = threadIdx.x;
  if (d < 3072) {
    const int z = d >> 10, i = d & 1023;
    const int bx = i & 31, by = i >> 5;
    const float* s = z == 0 ? W : (z == 1 ? ker : ker + (1u << 20));
    __bf16* o      = z == 0 ? Wt : (z == 1 ? k0t : k1t);
    __shared__ float tile[32][33];
    const int tx = t & 31, ty = t >> 5;       // 32 x 8
    const int x  = bx * 32 + tx;
    const int y0 = by * 32;
    for (int j = ty; j < 32; j += 8)
      tile[j][tx] = s[(size_t)(y0 + j) * 1024 + x];
    __syncthreads();
    const int x2 = y0 + tx;
    const int y2 = bx * 32;
    for (int j = ty; j < 32; j += 8)
      o[(size_t)(y2 + j) * 1024 + x2] = (__bf16)tile[tx][j];
  } else {
    const int f = d - 3072;                   // 0..32767
    const float* s = f < 16384 ? Lt : rnn;
    __bf16* o      = f < 16384 ? Ltb : rnnb;
    const size_t i = ((size_t)(f & 16383) * 256 + t) * 4;
    float4 v = *(const float4*)(s + i);
    bf16x4 h = {(__bf16)v.x, (__bf16)v.y, (__bf16)v.z, (__bf16)v.w};
    *(bf16x4*)(o + i) = h;
  }
}

// ---------------------------------------------------------------------------
// row softmax in place: 16384 rows x 2048 f32, one block per row.
// Also emits a bf16 copy of the row (PV GEMM A-operand).
// ---------------------------------------------------------------------------
__global__ __launch_bounds__(256)
void softmax_rows(float* __restrict__ Wt, __bf16* __restrict__ Pb) {
  const int t = threadIdx.x;
  float* p = Wt + (size_t)blockIdx.x * 2048;
  float4 a = ((float4*)p)[t];
  float4 b = ((float4*)p)[t + 256];

  float m = fmaxf(fmaxf(fmaxf(a.x, a.y), fmaxf(a.z, a.w)),
                  fmaxf(fmaxf(b.x, b.y), fmaxf(b.z, b.w)));
#pragma unroll
  for (int off = 32; off > 0; off >>= 1) m = fmaxf(m, __shfl_xor(m, off));
  __shared__ float red[8];
  if ((t & 63) == 0) red[t >> 6] = m;
  __syncthreads();
  m = fmaxf(fmaxf(red[0], red[1]), fmaxf(red[2], red[3]));

  a.x = __expf(a.x - m); a.y = __expf(a.y - m);
  a.z = __expf(a.z - m); a.w = __expf(a.w - m);
  b.x = __expf(b.x - m); b.y = __expf(b.y - m);
  b.z = __expf(b.z - m); b.w = __expf(b.w - m);
  float s = a.x + a.y + a.z + a.w + b.x + b.y + b.z + b.w;
#pragma unroll
  for (int off = 32; off > 0; off >>= 1) s += __shfl_xor(s, off);
  if ((t & 63) == 0) red[4 + (t >> 6)] = s;
  __syncthreads();
  s = red[4] + red[5] + red[6] + red[7];

  const float inv = 1.0f / s;
  a.x *= inv; a.y *= inv; a.z *= inv; a.w *= inv;
  b.x *= inv; b.y *= inv; b.z *= inv; b.w *= inv;
  ((float4*)p)[t] = a;
  ((float4*)p)[t + 256] = b;

  __bf16* pb = Pb + (size_t)blockIdx.x * 2048;
  bf16x4 ha = {(__bf16)a.x, (__bf16)a.y, (__bf16)a.z, (__bf16)a.w};
  bf16x4 hb = {(__bf16)b.x, (__bf16)b.y, (__bf16)b.z, (__bf16)b.w};
  *(bf16x4*)(pb + (size_t)t * 4) = ha;
  *(bf16x4*)(pb + (size_t)(t + 256) * 4) = hb;
}

// ---------------------------------------------------------------------------
extern "C" void kernel_launch(void* const* d_in, const int* in_sizes, int n_in,
                              void* d_out, int out_size, void* d_ws,
                              size_t ws_size, hipStream_t stream) {
  const float* Lt  = (const float*)d_in[0];  // [8,2048,1024]
  const float* rnn = (const float*)d_in[1];  // [8,2048,1024]
  const float* ker = (const float*)d_in[2];  // [2,1024,1024]
  const float* W   = (const float*)d_in[3];  // [1024,1024]

  float* ctx = (float*)d_out;                // [8,2048,1024]
  float* wts = ctx + (size_t)16777216;       // [8,2048,2048]

  __bf16* ws   = (__bf16*)d_ws;
  __bf16* Wt   = ws;                         // [1024,1024]  (n,d)   2 MiB
  __bf16* k0t  = Wt + (1u << 20);            // [1024,1024]          2 MiB
  __bf16* k1t  = k0t + (1u << 20);           // [1024,1024]          2 MiB
  __bf16* WQ   = k1t + (1u << 20);           // [8*2048,1024]       32 MiB
  __bf16* WK   = WQ + (16u << 20);           // [8*2048,1024]       32 MiB
  __bf16* WVt  = WK + (16u << 20);           // [8][1024][2048]     32 MiB
  __bf16* Ltb  = WVt + (16u << 20);          // [8,2048,1024] bf16  32 MiB
  __bf16* rnnb = Ltb + (16u << 20);          // [8,2048,1024] bf16  32 MiB
  __bf16* Pb = Ltb;  // P overlaps Ltb+rnnb (dead after proj_all/qk2) 64 MiB

  // 1) weights transpose+cvt AND Lt/rnn flat cvt, single launch
  cvt_all<<<36864, 256, 0, stream>>>(W, ker, Wt, k0t, k1t, Lt, Ltb, rnn, rnnb);

  // 2) WQ, WK, WVt in one launch (3 chained tiles per block)
  proj_all<<<256, 512, 0, stream>>>(rnnb, Ltb, Wt, k0t, k1t, WQ, WK, WVt);

  // 3) QK logits, *0.125 (2 chained tiles per block)
  qk2<<<256, 512, 0, stream>>>(WQ, WK, wts);

  // 4) softmax rows in place (+ bf16 copy for PV)
  softmax_rows<<<16384, 256, 0, stream>>>(wts, Pb);

  // 5) ctx[b,q,e] = sum_k P[b,q,k] * WVt[b,e,k]
  pv1<<<256, 512, 0, stream>>>(Pb, WVt, ctx);
}